// Round 8
// baseline (423.916 us; speedup 1.0000x reference)
//
#include <hip/hip_runtime.h>
#include <cstdint>
#include <cstddef>

#define N_NODES 102400
#define N_EDGES 1638400
#define DIM 128
#define SLOTS 48
#define NB 200          // buckets: node>>9, 512 nodes each (200*512 = 102400)
#define BKT_CAP 9216    // 8192 avg + 11 sigma
#define SC_BLOCKS 400   // 400 * 4096 = 1638400 edges
#define SC_EPT 16       // edges per thread (256 thr * 16 = 4096)

// f32 -> bf16 (round-to-nearest-even)
__device__ __forceinline__ unsigned short f2bf(float x) {
  unsigned u = __float_as_uint(x);
  u += 0x7FFFu + ((u >> 16) & 1u);
  return (unsigned short)(u >> 16);
}
__device__ __forceinline__ float bf_lo(unsigned u) {
  return __int_as_float((int)(u << 16));
}
__device__ __forceinline__ float bf_hi(unsigned u) {
  return __int_as_float((int)(u & 0xFFFF0000u));
}

// ===========================================================================
// V2 BUILD: bucket partition, LDS-atomic CSR fill (no per-edge global atomics)
// ===========================================================================

__global__ void k_initcur(int* __restrict__ dstCur, int* __restrict__ srcCur) {
  const int i = threadIdx.x;
  if (i < NB) {
    dstCur[i] = i * BKT_CAP;
    srcCur[i] = i * BKT_CAP;
  }
}

// Partition edges into 200 dst-buckets (packed (src<<9)|dstLocal) and
// 200 src-buckets (srcLocal as u16). One global atomic per block per bucket.
__global__ __launch_bounds__(256) void k_scatter(
    const int* __restrict__ esrc, const int* __restrict__ edst,
    int* __restrict__ dstCur, int* __restrict__ srcCur,
    unsigned* __restrict__ dstStage, unsigned short* __restrict__ srcStage) {
  __shared__ int histD[NB], histS[NB], baseD[NB], baseS[NB], locD[NB], locS[NB];
  const int tid = threadIdx.x;
  const int ebase = blockIdx.x * (256 * SC_EPT);

  for (int i = tid; i < NB; i += 256) {
    histD[i] = 0; histS[i] = 0; locD[i] = 0; locS[i] = 0;
  }
  __syncthreads();

  int s[SC_EPT], d[SC_EPT];
  #pragma unroll
  for (int k = 0; k < SC_EPT; ++k) {
    const int e = ebase + k * 256 + tid;
    s[k] = esrc[e];
    d[k] = edst[e];
    atomicAdd(&histD[d[k] >> 9], 1);
    atomicAdd(&histS[s[k] >> 9], 1);
  }
  __syncthreads();

  for (int i = tid; i < NB; i += 256) {
    baseD[i] = atomicAdd(&dstCur[i], histD[i]);
    baseS[i] = atomicAdd(&srcCur[i], histS[i]);
  }
  __syncthreads();

  #pragma unroll
  for (int k = 0; k < SC_EPT; ++k) {
    const int bd = d[k] >> 9;
    const int od = atomicAdd(&locD[bd], 1);
    dstStage[baseD[bd] + od] = ((unsigned)s[k] << 9) | (unsigned)(d[k] & 511);
    const int bs = s[k] >> 9;
    const int os = atomicAdd(&locS[bs], 1);
    srcStage[baseS[bs] + os] = (unsigned short)(s[k] & 511);
  }
}

// One block per dst-bucket: LDS count + LDS-cursor CSR fill (L2-local region).
__global__ __launch_bounds__(256) void k_csr(
    const unsigned* __restrict__ dstStage, const int* __restrict__ dstCur,
    int* __restrict__ cnt, unsigned* __restrict__ csr) {
  __shared__ int c[512], cur[512];
  const int b = blockIdx.x;
  const int tid = threadIdx.x;
  #pragma unroll
  for (int k = 0; k < 2; ++k) { c[tid + k * 256] = 0; cur[tid + k * 256] = 0; }
  __syncthreads();

  const int base = b * BKT_CAP;
  const int n = dstCur[b] - base;
  for (int i = tid; i < n; i += 256) {
    atomicAdd(&c[dstStage[base + i] & 511], 1);
  }
  __syncthreads();

  const int node0 = b * 512;
  #pragma unroll
  for (int k = 0; k < 2; ++k) cnt[node0 + tid + k * 256] = c[tid + k * 256];

  for (int i = tid; i < n; i += 256) {
    const unsigned e = dstStage[base + i];
    const int dloc = (int)(e & 511u);
    const int slot = atomicAdd(&cur[dloc], 1);
    csr[(size_t)(node0 + dloc) * SLOTS + slot] = (e >> 9) << 8;  // src byte off
  }
}

// One block per src-bucket: out-degree counts, coalesced write.
__global__ __launch_bounds__(256) void k_sdeg(
    const unsigned short* __restrict__ srcStage, const int* __restrict__ srcCur,
    int* __restrict__ deg_src) {
  __shared__ int c[512];
  const int b = blockIdx.x;
  const int tid = threadIdx.x;
  #pragma unroll
  for (int k = 0; k < 2; ++k) c[tid + k * 256] = 0;
  __syncthreads();
  const int base = b * BKT_CAP;
  const int n = srcCur[b] - base;
  for (int i = tid; i < n; i += 256) {
    atomicAdd(&c[srcStage[base + i]], 1);
  }
  __syncthreads();
  const int node0 = b * 512;
  #pragma unroll
  for (int k = 0; k < 2; ++k) deg_src[node0 + tid + k * 256] = c[tid + k * 256];
}

// fb[i] = bf16(x[i] * src_norm[row]) ; 4 elems/thread
__global__ void k_cvt_scale(const float* __restrict__ x,
                            const int* __restrict__ deg_src,
                            unsigned short* __restrict__ out) {
  const int i = blockIdx.x * blockDim.x + threadIdx.x;
  const int row = i >> 5;
  const int dg = deg_src[row];
  const float sn = rsqrtf((float)(dg > 0 ? dg : 1));
  const float4 v = reinterpret_cast<const float4*>(x)[i];
  ushort4 o;
  o.x = f2bf(v.x * sn);
  o.y = f2bf(v.y * sn);
  o.z = f2bf(v.z * sn);
  o.w = f2bf(v.w * sn);
  reinterpret_cast<ushort4*>(out)[i] = o;
}

// ---------------------------------------------------------------------------
// Fused layer (unchanged from round 6): padded-CSR, prescaled bf16 features.
// ---------------------------------------------------------------------------
template <int ACT>
__global__ __launch_bounds__(256, 8) void k_layer_n(
    const unsigned short* __restrict__ fb_in, const float* __restrict__ W,
    const float* __restrict__ bias, const int* __restrict__ cnt,
    const unsigned* __restrict__ csr, const int* __restrict__ deg_src,
    float* __restrict__ out, unsigned short* __restrict__ fb_out) {
  __shared__ float agg[32][132];

  const int tid  = threadIdx.x;
  const int lane = tid & 63;
  const int wid  = tid >> 6;
  const int q    = lane >> 4;
  const int li   = lane & 15;
  const int brow = blockIdx.x * 32;
  const char* fbase = reinterpret_cast<const char*>(fb_in);

  int gr = brow + wid;
  int c_cur = cnt[gr];
  unsigned pk_cur = (lane < c_cur) ? csr[(size_t)gr * SLOTS + lane] : 0u;

  for (int r = wid; r < 32; r += 4) {
    int c_nxt = 0;
    unsigned pk_nxt = 0u;
    if (r + 4 < 32) {
      c_nxt = cnt[gr + 4];
      if (lane < c_nxt) pk_nxt = csr[(size_t)(gr + 4) * SLOTS + lane];
    }

    float acc[8];
    #pragma unroll
    for (int i = 0; i < 8; ++i) acc[i] = 0.f;

    const int nq = (c_cur + 3) >> 2;
    #pragma unroll 4
    for (int j = 0; j < nq; ++j) {
      const int srcl = 4 * j + q;
      const int o = __shfl((int)pk_cur, srcl);
      if (srcl < c_cur) {
        const uint4 dd = *reinterpret_cast<const uint4*>(
            fbase + (size_t)(unsigned)o + (li << 4));
        acc[0] += bf_lo(dd.x);
        acc[1] += bf_hi(dd.x);
        acc[2] += bf_lo(dd.y);
        acc[3] += bf_hi(dd.y);
        acc[4] += bf_lo(dd.z);
        acc[5] += bf_hi(dd.z);
        acc[6] += bf_lo(dd.w);
        acc[7] += bf_hi(dd.w);
      }
    }

    const float dn = rsqrtf((float)(c_cur > 0 ? c_cur : 1));
    #pragma unroll
    for (int i = 0; i < 8; ++i) {
      acc[i] += __shfl_xor(acc[i], 32);
      acc[i] += __shfl_xor(acc[i], 16);
      acc[i] *= dn;
    }
    if (q == 0) {
      *reinterpret_cast<float4*>(&agg[r][li * 8]) =
          make_float4(acc[0], acc[1], acc[2], acc[3]);
      *reinterpret_cast<float4*>(&agg[r][li * 8 + 4]) =
          make_float4(acc[4], acc[5], acc[6], acc[7]);
    }

    gr += 4;
    c_cur = c_nxt;
    pk_cur = pk_nxt;
  }
  __syncthreads();

  const int tc = tid & 31;
  const int tr = tid >> 5;
  const int c0 = tc << 2;
  const float4* Wv = reinterpret_cast<const float4*>(W);

  float4 a4[4];
  #pragma unroll
  for (int i = 0; i < 4; ++i) a4[i] = make_float4(0.f, 0.f, 0.f, 0.f);

  #pragma unroll 2
  for (int k = 0; k < DIM; k += 4) {
    float4 w4[4];
    #pragma unroll
    for (int j = 0; j < 4; ++j) w4[j] = Wv[(k + j) * 32 + tc];
    #pragma unroll
    for (int i = 0; i < 4; ++i) {
      const float4 a = *reinterpret_cast<const float4*>(&agg[tr * 4 + i][k]);
      const float av[4] = {a.x, a.y, a.z, a.w};
      #pragma unroll
      for (int j = 0; j < 4; ++j) {
        a4[i].x = fmaf(av[j], w4[j].x, a4[i].x);
        a4[i].y = fmaf(av[j], w4[j].y, a4[i].y);
        a4[i].z = fmaf(av[j], w4[j].z, a4[i].z);
        a4[i].w = fmaf(av[j], w4[j].w, a4[i].w);
      }
    }
  }

  const float4 bv = *reinterpret_cast<const float4*>(bias + c0);
  #pragma unroll
  for (int i = 0; i < 4; ++i) {
    float4 v = a4[i];
    v.x += bv.x; v.y += bv.y; v.z += bv.z; v.w += bv.w;
    if (ACT == 0) {
      v.x = v.x > 0.f ? v.x : expm1f(v.x);
      v.y = v.y > 0.f ? v.y : expm1f(v.y);
      v.z = v.z > 0.f ? v.z : expm1f(v.z);
      v.w = v.w > 0.f ? v.w : expm1f(v.w);
    } else {
      float m = fmaxf(fmaxf(v.x, v.y), fmaxf(v.z, v.w));
      #pragma unroll
      for (int off = 16; off >= 1; off >>= 1) m = fmaxf(m, __shfl_xor(m, off));
      v.x = expf(v.x - m);
      v.y = expf(v.y - m);
      v.z = expf(v.z - m);
      v.w = expf(v.w - m);
      float s = v.x + v.y + v.z + v.w;
      #pragma unroll
      for (int off = 16; off >= 1; off >>= 1) s += __shfl_xor(s, off);
      const float inv = 1.0f / s;
      v.x *= inv; v.y *= inv; v.z *= inv; v.w *= inv;
    }
    const size_t row = (size_t)(brow + tr * 4 + i);
    *reinterpret_cast<float4*>(out + row * DIM + c0) = v;
    if (ACT == 0 && fb_out != nullptr) {
      const int dg = deg_src[row];
      const float sn = rsqrtf((float)(dg > 0 ? dg : 1));
      ushort4 o;
      o.x = f2bf(v.x * sn);
      o.y = f2bf(v.y * sn);
      o.z = f2bf(v.z * sn);
      o.w = f2bf(v.w * sn);
      *reinterpret_cast<ushort4*>(fb_out + row * DIM + c0) = o;
    }
  }
}

// ===========================================================================
// FALLBACK 1 (round-6): atomic padded-CSR build
// ===========================================================================
__global__ void k_build(const int* __restrict__ esrc, const int* __restrict__ edst,
                        int* __restrict__ deg_src, int* __restrict__ cnt,
                        unsigned* __restrict__ csr) {
  const int i = blockIdx.x * blockDim.x + threadIdx.x;
  if (i < N_EDGES) {
    const int s = esrc[i];
    const int d = edst[i];
    atomicAdd(&deg_src[s], 1);
    const int pos = atomicAdd(&cnt[d], 1);
    csr[(size_t)d * SLOTS + pos] = (unsigned)s << 8;
  }
}

// ===========================================================================
// FALLBACK 2 (round-5): compact CSR path
// ===========================================================================
__global__ void k_hist(const int* __restrict__ esrc, const int* __restrict__ edst,
                       int* __restrict__ deg_src, int* __restrict__ deg_dst) {
  const int i = blockIdx.x * blockDim.x + threadIdx.x;
  if (i < N_EDGES) {
    atomicAdd(&deg_src[esrc[i]], 1);
    atomicAdd(&deg_dst[edst[i]], 1);
  }
}

__global__ void k_bsum(const int* __restrict__ deg_dst, float* __restrict__ dst_norm,
                       int* __restrict__ bsum) {
  __shared__ int ws[4];
  const int tid  = threadIdx.x;
  const int base = blockIdx.x * 1024;
  int s = 0;
  #pragma unroll
  for (int t = 0; t < 4; ++t) {
    const int i = base + t * 256 + tid;
    const int d = deg_dst[i];
    s += d;
    dst_norm[i] = rsqrtf((float)(d > 0 ? d : 1));
  }
  #pragma unroll
  for (int off = 32; off >= 1; off >>= 1) s += __shfl_down(s, off);
  if ((tid & 63) == 0) ws[tid >> 6] = s;
  __syncthreads();
  if (tid == 0) bsum[blockIdx.x] = ws[0] + ws[1] + ws[2] + ws[3];
}

__global__ void k_bscan(const int* __restrict__ bsum, int* __restrict__ bpre) {
  const int tid = threadIdx.x;
  const int v = (tid < 100) ? bsum[tid] : 0;
  int s = v;
  #pragma unroll
  for (int off = 1; off < 64; off <<= 1) {
    const int t = __shfl_up(s, off);
    if ((tid & 63) >= off) s += t;
  }
  __shared__ int w0;
  if (tid == 63) w0 = s;
  __syncthreads();
  if (tid >= 64) s += w0;
  if (tid < 100) bpre[tid] = s - v;
}

__global__ void k_rowoff(const int* __restrict__ deg_dst, const int* __restrict__ bpre,
                         int* __restrict__ row_off, int* __restrict__ cursor) {
  __shared__ int wsum[16];
  const int tid  = threadIdx.x;
  const int lane = tid & 63;
  const int wid  = tid >> 6;
  const int i = blockIdx.x * 1024 + tid;
  const int d = deg_dst[i];
  int v = d;
  #pragma unroll
  for (int off = 1; off < 64; off <<= 1) {
    const int t = __shfl_up(v, off);
    if (lane >= off) v += t;
  }
  if (lane == 63) wsum[wid] = v;
  __syncthreads();
  if (tid < 16) {
    int w = wsum[tid];
    #pragma unroll
    for (int off = 1; off < 16; off <<= 1) {
      const int t = __shfl_up(w, off);
      if (tid >= off) w += t;
    }
    wsum[tid] = w;
  }
  __syncthreads();
  const int excl = bpre[blockIdx.x] + (wid > 0 ? wsum[wid - 1] : 0) + v - d;
  row_off[i] = excl;
  cursor[i]  = excl;
  if (i == N_NODES - 1) row_off[N_NODES] = excl + d;
}

__global__ void k_fill(const int* __restrict__ esrc, const int* __restrict__ edst,
                       const int* __restrict__ deg_src, int* __restrict__ cursor,
                       unsigned* __restrict__ csr_pk, int shift) {
  const int i = blockIdx.x * blockDim.x + threadIdx.x;
  if (i < N_EDGES) {
    const int s  = esrc[i];
    const int dg = deg_src[s];
    const int pos = atomicAdd(&cursor[edst[i]], 1);
    csr_pk[pos] = ((unsigned)s << shift) | ((unsigned)(dg > 63 ? 63 : dg) << 26);
  }
}

__global__ void k_cvt(const float* __restrict__ in, unsigned short* __restrict__ out) {
  const int i = blockIdx.x * blockDim.x + threadIdx.x;
  const float4 v = reinterpret_cast<const float4*>(in)[i];
  ushort4 o;
  o.x = f2bf(v.x);
  o.y = f2bf(v.y);
  o.z = f2bf(v.z);
  o.w = f2bf(v.w);
  reinterpret_cast<ushort4*>(out)[i] = o;
}

template <int ACT, int BF>
__global__ __launch_bounds__(256, 8) void k_layer(
    const void* __restrict__ featv, const float* __restrict__ W,
    const float* __restrict__ bias, const int* __restrict__ row_off,
    const unsigned* __restrict__ csr_pk, const float* __restrict__ dst_norm,
    float* __restrict__ out, unsigned short* __restrict__ fbn) {
  __shared__ float agg[32][132];

  const int tid  = threadIdx.x;
  const int lane = tid & 63;
  const int wid  = tid >> 6;
  const int brow = blockIdx.x * 32;
  const char* fbase = reinterpret_cast<const char*>(featv);

  for (int r = wid; r < 32; r += 4) {
    const int gr = brow + r;
    const int e0 = row_off[gr];
    const int e1 = row_off[gr + 1];
    float acc[8];
    #pragma unroll
    for (int i = 0; i < 8; ++i) acc[i] = 0.f;

    for (int e = e0; e < e1; e += 64) {
      const int cnt = min(64, e1 - e);
      const unsigned pk = (lane < cnt) ? csr_pk[e + lane] : 0u;
      const float wgt = (lane < cnt) ? rsqrtf((float)(pk >> 26)) : 0.f;
      const int off = (int)(pk & 0x03FFFFFFu);

      if (BF) {
        const int q  = lane >> 4;
        const int li = lane & 15;
        const int nq = (cnt + 3) >> 2;
        #pragma unroll 8
        for (int j = 0; j < nq; ++j) {
          const int srcl = 4 * j + q;
          const int o    = __shfl(off, srcl);
          const float ww = __shfl(wgt, srcl);
          const uint4 d = *reinterpret_cast<const uint4*>(
              fbase + (size_t)(unsigned)o + (li << 4));
          acc[0] = fmaf(ww, bf_lo(d.x), acc[0]);
          acc[1] = fmaf(ww, bf_hi(d.x), acc[1]);
          acc[2] = fmaf(ww, bf_lo(d.y), acc[2]);
          acc[3] = fmaf(ww, bf_hi(d.y), acc[3]);
          acc[4] = fmaf(ww, bf_lo(d.z), acc[4]);
          acc[5] = fmaf(ww, bf_hi(d.z), acc[5]);
          acc[6] = fmaf(ww, bf_lo(d.w), acc[6]);
          acc[7] = fmaf(ww, bf_hi(d.w), acc[7]);
        }
      } else {
        const int q  = lane >> 5;
        const int li = lane & 31;
        const int np = (cnt + 1) >> 1;
        #pragma unroll 8
        for (int j = 0; j < np; ++j) {
          const int srcl = 2 * j + q;
          const int o    = __shfl(off, srcl);
          const float ww = __shfl(wgt, srcl);
          const float4 v = *reinterpret_cast<const float4*>(
              fbase + (size_t)(unsigned)o + (li << 4));
          acc[0] = fmaf(ww, v.x, acc[0]);
          acc[1] = fmaf(ww, v.y, acc[1]);
          acc[2] = fmaf(ww, v.z, acc[2]);
          acc[3] = fmaf(ww, v.w, acc[3]);
        }
      }
    }

    const float dn = dst_norm[gr];
    if (BF) {
      #pragma unroll
      for (int i = 0; i < 8; ++i) {
        acc[i] += __shfl_xor(acc[i], 32);
        acc[i] += __shfl_xor(acc[i], 16);
        acc[i] *= dn;
      }
      if ((lane >> 4) == 0) {
        const int li = lane & 15;
        *reinterpret_cast<float4*>(&agg[r][li * 8]) =
            make_float4(acc[0], acc[1], acc[2], acc[3]);
        *reinterpret_cast<float4*>(&agg[r][li * 8 + 4]) =
            make_float4(acc[4], acc[5], acc[6], acc[7]);
      }
    } else {
      #pragma unroll
      for (int i = 0; i < 4; ++i) {
        acc[i] += __shfl_xor(acc[i], 32);
        acc[i] *= dn;
      }
      if ((lane >> 5) == 0) {
        const int li = lane & 31;
        *reinterpret_cast<float4*>(&agg[r][li * 4]) =
            make_float4(acc[0], acc[1], acc[2], acc[3]);
      }
    }
  }
  __syncthreads();

  const int tc = tid & 31;
  const int tr = tid >> 5;
  const int c0 = tc << 2;
  const float4* Wv = reinterpret_cast<const float4*>(W);

  float4 a4[4];
  #pragma unroll
  for (int i = 0; i < 4; ++i) a4[i] = make_float4(0.f, 0.f, 0.f, 0.f);

  #pragma unroll 2
  for (int k = 0; k < DIM; k += 4) {
    float4 w4[4];
    #pragma unroll
    for (int j = 0; j < 4; ++j) w4[j] = Wv[(k + j) * 32 + tc];
    #pragma unroll
    for (int i = 0; i < 4; ++i) {
      const float4 a = *reinterpret_cast<const float4*>(&agg[tr * 4 + i][k]);
      const float av[4] = {a.x, a.y, a.z, a.w};
      #pragma unroll
      for (int j = 0; j < 4; ++j) {
        a4[i].x = fmaf(av[j], w4[j].x, a4[i].x);
        a4[i].y = fmaf(av[j], w4[j].y, a4[i].y);
        a4[i].z = fmaf(av[j], w4[j].z, a4[i].z);
        a4[i].w = fmaf(av[j], w4[j].w, a4[i].w);
      }
    }
  }

  const float4 bv = *reinterpret_cast<const float4*>(bias + c0);
  #pragma unroll
  for (int i = 0; i < 4; ++i) {
    float4 v = a4[i];
    v.x += bv.x; v.y += bv.y; v.z += bv.z; v.w += bv.w;
    if (ACT == 0) {
      v.x = v.x > 0.f ? v.x : expm1f(v.x);
      v.y = v.y > 0.f ? v.y : expm1f(v.y);
      v.z = v.z > 0.f ? v.z : expm1f(v.z);
      v.w = v.w > 0.f ? v.w : expm1f(v.w);
    } else {
      float m = fmaxf(fmaxf(v.x, v.y), fmaxf(v.z, v.w));
      #pragma unroll
      for (int off = 16; off >= 1; off >>= 1) m = fmaxf(m, __shfl_xor(m, off));
      v.x = expf(v.x - m);
      v.y = expf(v.y - m);
      v.z = expf(v.z - m);
      v.w = expf(v.w - m);
      float s = v.x + v.y + v.z + v.w;
      #pragma unroll
      for (int off = 16; off >= 1; off >>= 1) s += __shfl_xor(s, off);
      const float inv = 1.0f / s;
      v.x *= inv; v.y *= inv; v.z *= inv; v.w *= inv;
    }
    const size_t row = (size_t)(brow + tr * 4 + i);
    *reinterpret_cast<float4*>(out + row * DIM + c0) = v;
    if (ACT == 0 && fbn != nullptr) {
      ushort4 o;
      o.x = f2bf(v.x);
      o.y = f2bf(v.y);
      o.z = f2bf(v.z);
      o.w = f2bf(v.w);
      *reinterpret_cast<ushort4*>(fbn + row * DIM + c0) = o;
    }
  }
}

// ---------------------------------------------------------------------------
static inline size_t align1k(size_t x) { return (x + 1023) & ~(size_t)1023; }

extern "C" void kernel_launch(void* const* d_in, const int* in_sizes, int n_in,
                              void* d_out, int out_size, void* d_ws,
                              size_t ws_size, hipStream_t stream) {
  const float* x  = (const float*)d_in[0];
  const float* W1 = (const float*)d_in[1];
  const float* b1 = (const float*)d_in[2];
  const float* W2 = (const float*)d_in[3];
  const float* b2 = (const float*)d_in[4];
  const float* W3 = (const float*)d_in[5];
  const float* b3 = (const float*)d_in[6];
  const int* esrc = (const int*)d_in[7];
  const int* edst = (const int*)d_in[8];

  float* y1 = (float*)d_out;
  float* y2 = y1 + (size_t)N_NODES * DIM;
  float* y3 = y2 + (size_t)N_NODES * DIM;

  const size_t fb_bytes = (size_t)N_NODES * DIM * 2;  // 26.2 MB

  // ---- V2 layout ----
  {
    char* ws = (char*)d_ws;
    int* dstCur = (int*)ws;                 ws += align1k(NB * 4);
    int* srcCur = (int*)ws;                 ws += align1k(NB * 4);
    int* cnt = (int*)ws;                    ws += align1k((size_t)N_NODES * 4);
    int* deg_src = (int*)ws;                ws += align1k((size_t)N_NODES * 4);
    unsigned* csr = (unsigned*)ws;          ws += align1k((size_t)N_NODES * SLOTS * 4);
    unsigned* dstStage = (unsigned*)ws;     ws += align1k((size_t)NB * BKT_CAP * 4);
    unsigned short* srcStage = (unsigned short*)ws;
                                            ws += align1k((size_t)NB * BKT_CAP * 2);
    unsigned short* fbA = (unsigned short*)ws;  ws += fb_bytes;
    unsigned short* fbB = (unsigned short*)ws;  ws += fb_bytes;
    const size_t need_v2 = (size_t)(ws - (char*)d_ws);

    if (ws_size >= need_v2) {
      k_initcur<<<1, 256, 0, stream>>>(dstCur, srcCur);
      k_scatter<<<SC_BLOCKS, 256, 0, stream>>>(esrc, edst, dstCur, srcCur,
                                               dstStage, srcStage);
      k_csr<<<NB, 256, 0, stream>>>(dstStage, dstCur, cnt, csr);
      k_sdeg<<<NB, 256, 0, stream>>>(srcStage, srcCur, deg_src);
      k_cvt_scale<<<N_NODES * DIM / 4 / 256, 256, 0, stream>>>(x, deg_src, fbA);

      k_layer_n<0><<<N_NODES / 32, 256, 0, stream>>>(
          fbA, W1, b1, cnt, csr, deg_src, y1, fbB);
      k_layer_n<0><<<N_NODES / 32, 256, 0, stream>>>(
          fbB, W2, b2, cnt, csr, deg_src, y2, fbA);
      k_layer_n<1><<<N_NODES / 32, 256, 0, stream>>>(
          fbA, W3, b3, cnt, csr, deg_src, y3, nullptr);
      return;
    }
  }

  // ---- Fallback 1: round-6 atomic padded-CSR build ----
  {
    char* ws = (char*)d_ws;
    int* deg_src = (int*)ws;  ws += (size_t)N_NODES * 4;
    int* cnt     = (int*)ws;  ws += (size_t)N_NODES * 4;
    unsigned* csr = (unsigned*)ws;  ws += (size_t)N_NODES * SLOTS * 4;
    unsigned short* fbA = (unsigned short*)ws;  ws += fb_bytes;
    unsigned short* fbB = (unsigned short*)ws;  ws += fb_bytes;
    const size_t need_v1 = (size_t)(ws - (char*)d_ws - 2 * fb_bytes) + 2 * fb_bytes;

    if (ws_size >= need_v1) {
      (void)hipMemsetAsync(deg_src, 0, (size_t)N_NODES * 2 * sizeof(int), stream);
      k_build<<<(N_EDGES + 255) / 256, 256, 0, stream>>>(esrc, edst, deg_src,
                                                         cnt, csr);
      k_cvt_scale<<<N_NODES * DIM / 4 / 256, 256, 0, stream>>>(x, deg_src, fbA);
      k_layer_n<0><<<N_NODES / 32, 256, 0, stream>>>(
          fbA, W1, b1, cnt, csr, deg_src, y1, fbB);
      k_layer_n<0><<<N_NODES / 32, 256, 0, stream>>>(
          fbB, W2, b2, cnt, csr, deg_src, y2, fbA);
      k_layer_n<1><<<N_NODES / 32, 256, 0, stream>>>(
          fbA, W3, b3, cnt, csr, deg_src, y3, nullptr);
      return;
    }
  }

  // ---- Fallback 2: compact CSR ----
  char* ws = (char*)d_ws;
  int* deg_src = (int*)ws;        ws += (size_t)N_NODES * 4;
  int* deg_dst = (int*)ws;        ws += (size_t)N_NODES * 4;
  int* row_off = (int*)ws;        ws += (size_t)(N_NODES + 32) * 4;
  int* cursor  = (int*)ws;        ws += (size_t)N_NODES * 4;
  float* dst_norm = (float*)ws;   ws += (size_t)N_NODES * 4;
  int* bsum = (int*)ws;           ws += 128 * 4;
  int* bpre = (int*)ws;           ws += 128 * 4;
  unsigned* csr_pk = (unsigned*)ws;  ws += (size_t)N_EDGES * 4;

  const size_t prep_bytes = (size_t)(ws - (char*)d_ws);
  const bool use_bf = ws_size >= prep_bytes + 2 * fb_bytes;

  unsigned short* fbA = (unsigned short*)ws;
  unsigned short* fbB = (unsigned short*)(ws + fb_bytes);

  (void)hipMemsetAsync(deg_src, 0, (size_t)N_NODES * 2 * sizeof(int), stream);

  k_hist<<<(N_EDGES + 255) / 256, 256, 0, stream>>>(esrc, edst, deg_src, deg_dst);
  k_bsum<<<N_NODES / 1024, 256, 0, stream>>>(deg_dst, dst_norm, bsum);
  k_bscan<<<1, 128, 0, stream>>>(bsum, bpre);
  k_rowoff<<<N_NODES / 1024, 1024, 0, stream>>>(deg_dst, bpre, row_off, cursor);
  k_fill<<<(N_EDGES + 255) / 256, 256, 0, stream>>>(esrc, edst, deg_src, cursor,
                                                    csr_pk, use_bf ? 8 : 9);

  if (use_bf) {
    k_cvt<<<(N_NODES * DIM / 4 + 255) / 256, 256, 0, stream>>>(x, fbA);
    k_layer<0, 1><<<N_NODES / 32, 256, 0, stream>>>(
        fbA, W1, b1, row_off, csr_pk, dst_norm, y1, fbB);
    k_layer<0, 1><<<N_NODES / 32, 256, 0, stream>>>(
        fbB, W2, b2, row_off, csr_pk, dst_norm, y2, fbA);
    k_layer<1, 1><<<N_NODES / 32, 256, 0, stream>>>(
        fbA, W3, b3, row_off, csr_pk, dst_norm, y3, nullptr);
  } else {
    k_layer<0, 0><<<N_NODES / 32, 256, 0, stream>>>(
        x, W1, b1, row_off, csr_pk, dst_norm, y1, nullptr);
    k_layer<0, 0><<<N_NODES / 32, 256, 0, stream>>>(
        y1, W2, b2, row_off, csr_pk, dst_norm, y2, nullptr);
    k_layer<1, 0><<<N_NODES / 32, 256, 0, stream>>>(
        y2, W3, b3, row_off, csr_pk, dst_norm, y3, nullptr);
  }
}

// Round 9
// 315.493 us; speedup vs baseline: 1.3437x; 1.3437x over previous
//
#include <hip/hip_runtime.h>
#include <hip/hip_fp16.h>
#include <cstdint>
#include <cstddef>

#define N_NODES 102400
#define N_EDGES 1638400
#define DIM 128
#define SLOTS 48
#define NB 200          // buckets: node>>9, 512 nodes each
#define BKT_CAP 9216
#define SC_BLOCKS 400   // 400 * 4096 = 1638400 edges
#define SC_EPT 16

typedef _Float16 f16x8 __attribute__((ext_vector_type(8)));
typedef float f32x4 __attribute__((ext_vector_type(4)));

// ===========================================================================
// BUILD (round-8 V2, plus full dummy-slot init in k_csr)
// ===========================================================================

__global__ void k_initcur(int* __restrict__ dstCur, int* __restrict__ srcCur) {
  const int i = threadIdx.x;
  if (i < NB) {
    dstCur[i] = i * BKT_CAP;
    srcCur[i] = i * BKT_CAP;
  }
}

__global__ __launch_bounds__(256) void k_scatter(
    const int* __restrict__ esrc, const int* __restrict__ edst,
    int* __restrict__ dstCur, int* __restrict__ srcCur,
    unsigned* __restrict__ dstStage, unsigned short* __restrict__ srcStage) {
  __shared__ int histD[NB], histS[NB], baseD[NB], baseS[NB], locD[NB], locS[NB];
  const int tid = threadIdx.x;
  const int ebase = blockIdx.x * (256 * SC_EPT);

  for (int i = tid; i < NB; i += 256) {
    histD[i] = 0; histS[i] = 0; locD[i] = 0; locS[i] = 0;
  }
  __syncthreads();

  int s[SC_EPT], d[SC_EPT];
  #pragma unroll
  for (int k = 0; k < SC_EPT; ++k) {
    const int e = ebase + k * 256 + tid;
    s[k] = esrc[e];
    d[k] = edst[e];
    atomicAdd(&histD[d[k] >> 9], 1);
    atomicAdd(&histS[s[k] >> 9], 1);
  }
  __syncthreads();

  for (int i = tid; i < NB; i += 256) {
    baseD[i] = atomicAdd(&dstCur[i], histD[i]);
    baseS[i] = atomicAdd(&srcCur[i], histS[i]);
  }
  __syncthreads();

  #pragma unroll
  for (int k = 0; k < SC_EPT; ++k) {
    const int bd = d[k] >> 9;
    const int od = atomicAdd(&locD[bd], 1);
    dstStage[baseD[bd] + od] = ((unsigned)s[k] << 9) | (unsigned)(d[k] & 511);
    const int bs = s[k] >> 9;
    const int os = atomicAdd(&locS[bs], 1);
    srcStage[baseS[bs] + os] = (unsigned short)(s[k] & 511);
  }
}

// One block per dst-bucket: init ALL slots to dummy (zero-row ptr), then
// LDS count + LDS-cursor CSR fill.
__global__ __launch_bounds__(256) void k_csr(
    const unsigned* __restrict__ dstStage, const int* __restrict__ dstCur,
    int* __restrict__ cnt, unsigned* __restrict__ csr) {
  __shared__ int c[512], cur[512];
  const int b = blockIdx.x;
  const int tid = threadIdx.x;
  const int node0 = b * 512;

  // dummy init: every slot points at the zero row (byte offset N_NODES*256)
  const unsigned dummy = (unsigned)N_NODES << 8;
  uint4 dv;
  dv.x = dummy; dv.y = dummy; dv.z = dummy; dv.w = dummy;
  uint4* c4 = reinterpret_cast<uint4*>(csr + (size_t)node0 * SLOTS);
  for (int i = tid; i < 512 * SLOTS / 4; i += 256) c4[i] = dv;

  #pragma unroll
  for (int k = 0; k < 2; ++k) { c[tid + k * 256] = 0; cur[tid + k * 256] = 0; }
  __syncthreads();

  const int base = b * BKT_CAP;
  const int n = dstCur[b] - base;
  for (int i = tid; i < n; i += 256) {
    atomicAdd(&c[dstStage[base + i] & 511], 1);
  }
  __syncthreads();

  #pragma unroll
  for (int k = 0; k < 2; ++k) cnt[node0 + tid + k * 256] = c[tid + k * 256];

  for (int i = tid; i < n; i += 256) {
    const unsigned e = dstStage[base + i];
    const int dloc = (int)(e & 511u);
    const int slot = atomicAdd(&cur[dloc], 1);
    csr[(size_t)(node0 + dloc) * SLOTS + slot] = (e >> 9) << 8;  // src byte off
  }
}

__global__ __launch_bounds__(256) void k_sdeg(
    const unsigned short* __restrict__ srcStage, const int* __restrict__ srcCur,
    int* __restrict__ deg_src) {
  __shared__ int c[512];
  const int b = blockIdx.x;
  const int tid = threadIdx.x;
  #pragma unroll
  for (int k = 0; k < 2; ++k) c[tid + k * 256] = 0;
  __syncthreads();
  const int base = b * BKT_CAP;
  const int n = srcCur[b] - base;
  for (int i = tid; i < n; i += 256) {
    atomicAdd(&c[srcStage[base + i]], 1);
  }
  __syncthreads();
  const int node0 = b * 512;
  #pragma unroll
  for (int k = 0; k < 2; ++k) deg_src[node0 + tid + k * 256] = c[tid + k * 256];
}

// fb[i] = f16(x[i] * src_norm[row]) ; 4 elems/thread
__global__ void k_cvt_scale(const float* __restrict__ x,
                            const int* __restrict__ deg_src,
                            unsigned short* __restrict__ out) {
  const int i = blockIdx.x * blockDim.x + threadIdx.x;
  const int row = i >> 5;
  const int dg = deg_src[row];
  const float sn = rsqrtf((float)(dg > 0 ? dg : 1));
  const float4 v = reinterpret_cast<const float4*>(x)[i];
  ushort4 o;
  o.x = __half_as_ushort(__float2half_rn(v.x * sn));
  o.y = __half_as_ushort(__float2half_rn(v.y * sn));
  o.z = __half_as_ushort(__float2half_rn(v.z * sn));
  o.w = __half_as_ushort(__float2half_rn(v.w * sn));
  reinterpret_cast<ushort4*>(out)[i] = o;
}

// ===========================================================================
// Fused layer: guard-free dual-row f16 gather + MFMA f16 GEMM
// ===========================================================================
template <int ACT>
__global__ __launch_bounds__(256, 6) void k_layer_m(
    const unsigned short* __restrict__ fb_in, const float* __restrict__ W,
    const float* __restrict__ bias, const int* __restrict__ cnt,
    const unsigned* __restrict__ csr, const int* __restrict__ deg_src,
    float* __restrict__ out, unsigned short* __restrict__ fb_out) {
  __shared__ float buf[32][132];  // 16.9 KB; first 8.7 KB aliased as f16 agg[32][136]
  __half* aggH = reinterpret_cast<__half*>(&buf[0][0]);

  const int tid  = threadIdx.x;
  const int lane = tid & 63;
  const int wid  = tid >> 6;
  const int q    = lane >> 4;
  const int li   = lane & 15;
  const int brow = blockIdx.x * 32;
  const char* fbase = reinterpret_cast<const char*>(fb_in);

  // ---- phase 1: gather, 8 rows/wave as 4 interleaved pairs ----
  int grA = brow + wid;
  int grB = grA + 4;
  int cA = cnt[grA], cB = cnt[grB];
  unsigned pkA = (lane < SLOTS) ? csr[(size_t)grA * SLOTS + lane] : 0u;
  unsigned pkB = (lane < SLOTS) ? csr[(size_t)grB * SLOTS + lane] : 0u;

  #pragma unroll
  for (int p = 0; p < 4; ++p) {
    int ncA = 0, ncB = 0;
    unsigned npA = 0u, npB = 0u;
    if (p < 3) {
      ncA = cnt[grA + 8];
      ncB = cnt[grB + 8];
      if (lane < SLOTS) {
        npA = csr[(size_t)(grA + 8) * SLOTS + lane];
        npB = csr[(size_t)(grB + 8) * SLOTS + lane];
      }
    }

    __half2 accA[4], accB[4];
    #pragma unroll
    for (int i = 0; i < 4; ++i) {
      accA[i] = __float2half2_rn(0.0f);
      accB[i] = __float2half2_rn(0.0f);
    }

    const int cmax = cA > cB ? cA : cB;
    const int nq = (cmax + 3) >> 2;   // dummy slots are zero rows: no guards
    #pragma unroll 4
    for (int j = 0; j < nq; ++j) {
      const int sl = 4 * j + q;
      const int oA = __shfl((int)pkA, sl);
      const int oB = __shfl((int)pkB, sl);
      const uint4 va = *reinterpret_cast<const uint4*>(
          fbase + (size_t)(unsigned)oA + (li << 4));
      const uint4 vb = *reinterpret_cast<const uint4*>(
          fbase + (size_t)(unsigned)oB + (li << 4));
      accA[0] = __hadd2(accA[0], *reinterpret_cast<const __half2*>(&va.x));
      accA[1] = __hadd2(accA[1], *reinterpret_cast<const __half2*>(&va.y));
      accA[2] = __hadd2(accA[2], *reinterpret_cast<const __half2*>(&va.z));
      accA[3] = __hadd2(accA[3], *reinterpret_cast<const __half2*>(&va.w));
      accB[0] = __hadd2(accB[0], *reinterpret_cast<const __half2*>(&vb.x));
      accB[1] = __hadd2(accB[1], *reinterpret_cast<const __half2*>(&vb.y));
      accB[2] = __hadd2(accB[2], *reinterpret_cast<const __half2*>(&vb.z));
      accB[3] = __hadd2(accB[3], *reinterpret_cast<const __half2*>(&vb.w));
    }

    // reduce quarters (packed)
    #pragma unroll
    for (int i = 0; i < 4; ++i) {
      int t = __shfl_xor(*reinterpret_cast<int*>(&accA[i]), 32);
      accA[i] = __hadd2(accA[i], *reinterpret_cast<__half2*>(&t));
      t = __shfl_xor(*reinterpret_cast<int*>(&accA[i]), 16);
      accA[i] = __hadd2(accA[i], *reinterpret_cast<__half2*>(&t));
      t = __shfl_xor(*reinterpret_cast<int*>(&accB[i]), 32);
      accB[i] = __hadd2(accB[i], *reinterpret_cast<__half2*>(&t));
      t = __shfl_xor(*reinterpret_cast<int*>(&accB[i]), 16);
      accB[i] = __hadd2(accB[i], *reinterpret_cast<__half2*>(&t));
    }

    if (q == 0) {
      const __half2 dA = __float2half2_rn(rsqrtf((float)(cA > 0 ? cA : 1)));
      const __half2 dB = __float2half2_rn(rsqrtf((float)(cB > 0 ? cB : 1)));
      uint4 sa, sb;
      __half2 h;
      h = __hmul2(accA[0], dA); sa.x = *reinterpret_cast<unsigned*>(&h);
      h = __hmul2(accA[1], dA); sa.y = *reinterpret_cast<unsigned*>(&h);
      h = __hmul2(accA[2], dA); sa.z = *reinterpret_cast<unsigned*>(&h);
      h = __hmul2(accA[3], dA); sa.w = *reinterpret_cast<unsigned*>(&h);
      h = __hmul2(accB[0], dB); sb.x = *reinterpret_cast<unsigned*>(&h);
      h = __hmul2(accB[1], dB); sb.y = *reinterpret_cast<unsigned*>(&h);
      h = __hmul2(accB[2], dB); sb.z = *reinterpret_cast<unsigned*>(&h);
      h = __hmul2(accB[3], dB); sb.w = *reinterpret_cast<unsigned*>(&h);
      *reinterpret_cast<uint4*>(aggH + (size_t)(wid + 8 * p) * 136 + li * 8) = sa;
      *reinterpret_cast<uint4*>(aggH + (size_t)(wid + 8 * p + 4) * 136 + li * 8) = sb;
    }

    grA += 8; grB += 8;
    cA = ncA; cB = ncB;
    pkA = npA; pkB = npB;
  }
  __syncthreads();

  // ---- phase 2: MFMA GEMM. wave wid owns cols [32*wid, 32*wid+32) ----
  // A: agg[32][128] f16 in LDS. B: W[128][128] f32 in global -> f16 frags.
  f32x4 acc00 = {0.f, 0.f, 0.f, 0.f};
  f32x4 acc01 = {0.f, 0.f, 0.f, 0.f};
  f32x4 acc10 = {0.f, 0.f, 0.f, 0.f};
  f32x4 acc11 = {0.f, 0.f, 0.f, 0.f};
  const int colbase = wid * 32 + li;

  #pragma unroll
  for (int kc = 0; kc < 4; ++kc) {
    const int k0 = kc * 32 + q * 8;
    const f16x8 a0 = *reinterpret_cast<const f16x8*>(aggH + (size_t)li * 136 + k0);
    const f16x8 a1 =
        *reinterpret_cast<const f16x8*>(aggH + (size_t)(16 + li) * 136 + k0);
    const float* w0 = W + (size_t)k0 * DIM + colbase;
    f16x8 b0, b1;
    #pragma unroll
    for (int e = 0; e < 8; ++e) {
      b0[e] = (_Float16)w0[e * DIM];
      b1[e] = (_Float16)w0[e * DIM + 16];
    }
    acc00 = __builtin_amdgcn_mfma_f32_16x16x32_f16(a0, b0, acc00, 0, 0, 0);
    acc01 = __builtin_amdgcn_mfma_f32_16x16x32_f16(a0, b1, acc01, 0, 0, 0);
    acc10 = __builtin_amdgcn_mfma_f32_16x16x32_f16(a1, b0, acc10, 0, 0, 0);
    acc11 = __builtin_amdgcn_mfma_f32_16x16x32_f16(a1, b1, acc11, 0, 0, 0);
  }
  __syncthreads();  // all aggH reads done; buf may be overwritten

  // D fragments -> buf (f32). D: col = lane&15, row = (lane>>4)*4 + reg.
  #pragma unroll
  for (int r = 0; r < 4; ++r) {
    const int row0 = q * 4 + r;
    buf[row0][colbase] = acc00[r];
    buf[row0][colbase + 16] = acc01[r];
    buf[row0 + 16][colbase] = acc10[r];
    buf[row0 + 16][colbase + 16] = acc11[r];
  }
  __syncthreads();

  // ---- epilogue: bias + activation + store (+ f16 prescaled copy) ----
  const int tc = tid & 31;
  const int tr = tid >> 5;
  const int c0 = tc << 2;
  const float4 bv = *reinterpret_cast<const float4*>(bias + c0);
  #pragma unroll
  for (int i = 0; i < 4; ++i) {
    const int row = tr * 4 + i;
    float4 v = *reinterpret_cast<const float4*>(&buf[row][c0]);
    v.x += bv.x; v.y += bv.y; v.z += bv.z; v.w += bv.w;
    if (ACT == 0) {
      v.x = v.x > 0.f ? v.x : expm1f(v.x);
      v.y = v.y > 0.f ? v.y : expm1f(v.y);
      v.z = v.z > 0.f ? v.z : expm1f(v.z);
      v.w = v.w > 0.f ? v.w : expm1f(v.w);
    } else {
      float m = fmaxf(fmaxf(v.x, v.y), fmaxf(v.z, v.w));
      #pragma unroll
      for (int off = 16; off >= 1; off >>= 1) m = fmaxf(m, __shfl_xor(m, off));
      v.x = expf(v.x - m);
      v.y = expf(v.y - m);
      v.z = expf(v.z - m);
      v.w = expf(v.w - m);
      float s = v.x + v.y + v.z + v.w;
      #pragma unroll
      for (int off = 16; off >= 1; off >>= 1) s += __shfl_xor(s, off);
      const float inv = 1.0f / s;
      v.x *= inv; v.y *= inv; v.z *= inv; v.w *= inv;
    }
    const size_t grow = (size_t)(brow + row);
    *reinterpret_cast<float4*>(out + grow * DIM + c0) = v;
    if (ACT == 0 && fb_out != nullptr) {
      const int dg = deg_src[grow];
      const float sn = rsqrtf((float)(dg > 0 ? dg : 1));
      ushort4 o;
      o.x = __half_as_ushort(__float2half_rn(v.x * sn));
      o.y = __half_as_ushort(__float2half_rn(v.y * sn));
      o.z = __half_as_ushort(__float2half_rn(v.z * sn));
      o.w = __half_as_ushort(__float2half_rn(v.w * sn));
      *reinterpret_cast<ushort4*>(fb_out + grow * DIM + c0) = o;
    }
  }
}

// ===========================================================================
// FALLBACK build: full dummy fill + per-edge atomic padded-CSR
// ===========================================================================
__global__ void k_dummyfill(unsigned* __restrict__ csr) {
  const unsigned dummy = (unsigned)N_NODES << 8;
  uint4 dv;
  dv.x = dummy; dv.y = dummy; dv.z = dummy; dv.w = dummy;
  const int i = blockIdx.x * blockDim.x + threadIdx.x;
  if (i < N_NODES * SLOTS / 4) reinterpret_cast<uint4*>(csr)[i] = dv;
}

__global__ void k_build(const int* __restrict__ esrc, const int* __restrict__ edst,
                        int* __restrict__ deg_src, int* __restrict__ cnt,
                        unsigned* __restrict__ csr) {
  const int i = blockIdx.x * blockDim.x + threadIdx.x;
  if (i < N_EDGES) {
    const int s = esrc[i];
    const int d = edst[i];
    atomicAdd(&deg_src[s], 1);
    const int pos = atomicAdd(&cnt[d], 1);
    csr[(size_t)d * SLOTS + pos] = (unsigned)s << 8;
  }
}

// ---------------------------------------------------------------------------
static inline size_t align1k(size_t x) { return (x + 1023) & ~(size_t)1023; }

extern "C" void kernel_launch(void* const* d_in, const int* in_sizes, int n_in,
                              void* d_out, int out_size, void* d_ws,
                              size_t ws_size, hipStream_t stream) {
  const float* x  = (const float*)d_in[0];
  const float* W1 = (const float*)d_in[1];
  const float* b1 = (const float*)d_in[2];
  const float* W2 = (const float*)d_in[3];
  const float* b2 = (const float*)d_in[4];
  const float* W3 = (const float*)d_in[5];
  const float* b3 = (const float*)d_in[6];
  const int* esrc = (const int*)d_in[7];
  const int* edst = (const int*)d_in[8];

  float* y1 = (float*)d_out;
  float* y2 = y1 + (size_t)N_NODES * DIM;
  float* y3 = y2 + (size_t)N_NODES * DIM;

  // f16 tables have one extra zero "dummy" row
  const size_t fb_bytes = (size_t)(N_NODES + 1) * DIM * 2;  // ~26.2 MB

  // ---- V2 layout ----
  {
    char* ws = (char*)d_ws;
    int* dstCur = (int*)ws;                 ws += align1k(NB * 4);
    int* srcCur = (int*)ws;                 ws += align1k(NB * 4);
    int* cnt = (int*)ws;                    ws += align1k((size_t)N_NODES * 4);
    int* deg_src = (int*)ws;                ws += align1k((size_t)N_NODES * 4);
    unsigned* csr = (unsigned*)ws;          ws += align1k((size_t)N_NODES * SLOTS * 4);
    unsigned* dstStage = (unsigned*)ws;     ws += align1k((size_t)NB * BKT_CAP * 4);
    unsigned short* srcStage = (unsigned short*)ws;
                                            ws += align1k((size_t)NB * BKT_CAP * 2);
    unsigned short* fbA = (unsigned short*)ws;  ws += align1k(fb_bytes);
    unsigned short* fbB = (unsigned short*)ws;  ws += align1k(fb_bytes);
    const size_t need_v2 = (size_t)(ws - (char*)d_ws);

    if (ws_size >= need_v2) {
      k_initcur<<<1, 256, 0, stream>>>(dstCur, srcCur);
      k_scatter<<<SC_BLOCKS, 256, 0, stream>>>(esrc, edst, dstCur, srcCur,
                                               dstStage, srcStage);
      k_csr<<<NB, 256, 0, stream>>>(dstStage, dstCur, cnt, csr);
      k_sdeg<<<NB, 256, 0, stream>>>(srcStage, srcCur, deg_src);
      k_cvt_scale<<<N_NODES * DIM / 4 / 256, 256, 0, stream>>>(x, deg_src, fbA);
      // zero the dummy rows of both tables
      (void)hipMemsetAsync(fbA + (size_t)N_NODES * DIM, 0, DIM * 2, stream);
      (void)hipMemsetAsync(fbB + (size_t)N_NODES * DIM, 0, DIM * 2, stream);

      k_layer_m<0><<<N_NODES / 32, 256, 0, stream>>>(
          fbA, W1, b1, cnt, csr, deg_src, y1, fbB);
      k_layer_m<0><<<N_NODES / 32, 256, 0, stream>>>(
          fbB, W2, b2, cnt, csr, deg_src, y2, fbA);
      k_layer_m<1><<<N_NODES / 32, 256, 0, stream>>>(
          fbA, W3, b3, cnt, csr, deg_src, y3, nullptr);
      return;
    }
  }

  // ---- Fallback: atomic padded-CSR build + same f16 layers ----
  {
    char* ws = (char*)d_ws;
    int* cnt     = (int*)ws;  ws += (size_t)N_NODES * 4;
    int* deg_src = (int*)ws;  ws += (size_t)N_NODES * 4;
    unsigned* csr = (unsigned*)ws;  ws += (size_t)N_NODES * SLOTS * 4;
    unsigned short* fbA = (unsigned short*)ws;  ws += align1k(fb_bytes);
    unsigned short* fbB = (unsigned short*)ws;  ws += align1k(fb_bytes);

    (void)hipMemsetAsync(cnt, 0, (size_t)N_NODES * 2 * sizeof(int), stream);
    k_dummyfill<<<(N_NODES * SLOTS / 4 + 255) / 256, 256, 0, stream>>>(csr);
    k_build<<<(N_EDGES + 255) / 256, 256, 0, stream>>>(esrc, edst, deg_src,
                                                       cnt, csr);
    k_cvt_scale<<<N_NODES * DIM / 4 / 256, 256, 0, stream>>>(x, deg_src, fbA);
    (void)hipMemsetAsync(fbA + (size_t)N_NODES * DIM, 0, DIM * 2, stream);
    (void)hipMemsetAsync(fbB + (size_t)N_NODES * DIM, 0, DIM * 2, stream);

    k_layer_m<0><<<N_NODES / 32, 256, 0, stream>>>(
        fbA, W1, b1, cnt, csr, deg_src, y1, fbB);
    k_layer_m<0><<<N_NODES / 32, 256, 0, stream>>>(
        fbB, W2, b2, cnt, csr, deg_src, y2, fbA);
    k_layer_m<1><<<N_NODES / 32, 256, 0, stream>>>(
        fbA, W3, b3, cnt, csr, deg_src, y3, nullptr);
  }
}

// Round 10
// 296.019 us; speedup vs baseline: 1.4321x; 1.0658x over previous
//
#include <hip/hip_runtime.h>
#include <hip/hip_fp16.h>
#include <cstdint>
#include <cstddef>

#define N_NODES 102400
#define N_EDGES 1638400
#define DIM 128
#define SLOTS 48
#define NB 200          // buckets: node>>9, 512 nodes each
#define BKT_CAP 9216
#define SC_BLOCKS 400   // 400 * 4096 = 1638400 edges
#define SC_EPT 16

typedef _Float16 f16x8 __attribute__((ext_vector_type(8)));
typedef float f32x4 __attribute__((ext_vector_type(4)));

// ===========================================================================
// BUILD: bucket partition, LDS-atomic CSR fill (no per-edge global atomics)
// ===========================================================================

// init cursors + zero the dummy rows of both f16 tables (replaces in-graph
// hipMemsetAsync, which showed up as expensive fillBufferAligned dispatches)
__global__ void k_initcur(int* __restrict__ dstCur, int* __restrict__ srcCur,
                          unsigned short* __restrict__ fbA,
                          unsigned short* __restrict__ fbB) {
  const int i = threadIdx.x;
  if (i < NB) {
    dstCur[i] = i * BKT_CAP;
    srcCur[i] = i * BKT_CAP;
  }
  if (i < 64) {
    reinterpret_cast<unsigned*>(fbA + (size_t)N_NODES * DIM)[i] = 0u;
  } else if (i < 128) {
    reinterpret_cast<unsigned*>(fbB + (size_t)N_NODES * DIM)[i - 64] = 0u;
  }
}

__global__ __launch_bounds__(256) void k_scatter(
    const int* __restrict__ esrc, const int* __restrict__ edst,
    int* __restrict__ dstCur, int* __restrict__ srcCur,
    unsigned* __restrict__ dstStage, unsigned short* __restrict__ srcStage) {
  __shared__ int histD[NB], histS[NB], baseD[NB], baseS[NB], locD[NB], locS[NB];
  const int tid = threadIdx.x;
  const int ebase = blockIdx.x * (256 * SC_EPT);

  for (int i = tid; i < NB; i += 256) {
    histD[i] = 0; histS[i] = 0; locD[i] = 0; locS[i] = 0;
  }
  __syncthreads();

  int s[SC_EPT], d[SC_EPT];
  #pragma unroll
  for (int k = 0; k < SC_EPT; ++k) {
    const int e = ebase + k * 256 + tid;
    s[k] = esrc[e];
    d[k] = edst[e];
    atomicAdd(&histD[d[k] >> 9], 1);
    atomicAdd(&histS[s[k] >> 9], 1);
  }
  __syncthreads();

  for (int i = tid; i < NB; i += 256) {
    baseD[i] = atomicAdd(&dstCur[i], histD[i]);
    baseS[i] = atomicAdd(&srcCur[i], histS[i]);
  }
  __syncthreads();

  #pragma unroll
  for (int k = 0; k < SC_EPT; ++k) {
    const int bd = d[k] >> 9;
    const int od = atomicAdd(&locD[bd], 1);
    dstStage[baseD[bd] + od] = ((unsigned)s[k] << 9) | (unsigned)(d[k] & 511);
    const int bs = s[k] >> 9;
    const int os = atomicAdd(&locS[bs], 1);
    srcStage[baseS[bs] + os] = (unsigned short)(s[k] & 511);
  }
}

// One block per dst-bucket: init ALL slots to dummy (zero-row ptr), then
// LDS count + LDS-cursor CSR fill.
__global__ __launch_bounds__(256) void k_csr(
    const unsigned* __restrict__ dstStage, const int* __restrict__ dstCur,
    int* __restrict__ cnt, unsigned* __restrict__ csr) {
  __shared__ int c[512], cur[512];
  const int b = blockIdx.x;
  const int tid = threadIdx.x;
  const int node0 = b * 512;

  const unsigned dummy = (unsigned)N_NODES << 8;
  uint4 dv;
  dv.x = dummy; dv.y = dummy; dv.z = dummy; dv.w = dummy;
  uint4* c4 = reinterpret_cast<uint4*>(csr + (size_t)node0 * SLOTS);
  for (int i = tid; i < 512 * SLOTS / 4; i += 256) c4[i] = dv;

  #pragma unroll
  for (int k = 0; k < 2; ++k) { c[tid + k * 256] = 0; cur[tid + k * 256] = 0; }
  __syncthreads();

  const int base = b * BKT_CAP;
  const int n = dstCur[b] - base;
  for (int i = tid; i < n; i += 256) {
    atomicAdd(&c[dstStage[base + i] & 511], 1);
  }
  __syncthreads();

  #pragma unroll
  for (int k = 0; k < 2; ++k) cnt[node0 + tid + k * 256] = c[tid + k * 256];

  for (int i = tid; i < n; i += 256) {
    const unsigned e = dstStage[base + i];
    const int dloc = (int)(e & 511u);
    const int slot = atomicAdd(&cur[dloc], 1);
    csr[(size_t)(node0 + dloc) * SLOTS + slot] = (e >> 9) << 8;  // src byte off
  }
}

__global__ __launch_bounds__(256) void k_sdeg(
    const unsigned short* __restrict__ srcStage, const int* __restrict__ srcCur,
    int* __restrict__ deg_src) {
  __shared__ int c[512];
  const int b = blockIdx.x;
  const int tid = threadIdx.x;
  #pragma unroll
  for (int k = 0; k < 2; ++k) c[tid + k * 256] = 0;
  __syncthreads();
  const int base = b * BKT_CAP;
  const int n = srcCur[b] - base;
  for (int i = tid; i < n; i += 256) {
    atomicAdd(&c[srcStage[base + i]], 1);
  }
  __syncthreads();
  const int node0 = b * 512;
  #pragma unroll
  for (int k = 0; k < 2; ++k) deg_src[node0 + tid + k * 256] = c[tid + k * 256];
}

// fb[i] = f16(x[i] * src_norm[row]) ; 4 elems/thread
__global__ void k_cvt_scale(const float* __restrict__ x,
                            const int* __restrict__ deg_src,
                            unsigned short* __restrict__ out) {
  const int i = blockIdx.x * blockDim.x + threadIdx.x;
  const int row = i >> 5;
  const int dg = deg_src[row];
  const float sn = rsqrtf((float)(dg > 0 ? dg : 1));
  const float4 v = reinterpret_cast<const float4*>(x)[i];
  ushort4 o;
  o.x = __half_as_ushort(__float2half_rn(v.x * sn));
  o.y = __half_as_ushort(__float2half_rn(v.y * sn));
  o.z = __half_as_ushort(__float2half_rn(v.z * sn));
  o.w = __half_as_ushort(__float2half_rn(v.w * sn));
  reinterpret_cast<ushort4*>(out)[i] = o;
}

// ===========================================================================
// Fused layer: guard-free 4-row-interleaved f16 gather + MFMA f16 GEMM
// ===========================================================================
template <int ACT>
__global__ __launch_bounds__(256, 6) void k_layer_m(
    const unsigned short* __restrict__ fb_in, const float* __restrict__ W,
    const float* __restrict__ bias, const int* __restrict__ cnt,
    const unsigned* __restrict__ csr, const int* __restrict__ deg_src,
    float* __restrict__ out, unsigned short* __restrict__ fb_out) {
  __shared__ float buf[32][132];  // 16.9 KB; aliased as f16 agg[32][136]
  __half* aggH = reinterpret_cast<__half*>(&buf[0][0]);

  const int tid  = threadIdx.x;
  const int lane = tid & 63;
  const int wid  = tid >> 6;
  const int q    = lane >> 4;
  const int li   = lane & 15;
  const int brow = blockIdx.x * 32;
  const char* fbase = reinterpret_cast<const char*>(fb_in);

  // ---- phase 1: gather. Wave owns rows wid+4k, k=0..7; 4-row interleave. ----
  int c_[8];
  unsigned pk_[8];
  #pragma unroll
  for (int k = 0; k < 8; ++k) {
    const int gr = brow + wid + 4 * k;
    c_[k] = cnt[gr];
    pk_[k] = (lane < SLOTS) ? csr[(size_t)gr * SLOTS + lane] : 0u;
  }

  #pragma unroll
  for (int pass = 0; pass < 2; ++pass) {
    const int kb = pass * 4;
    __half2 acc[4][4];
    #pragma unroll
    for (int k = 0; k < 4; ++k)
      #pragma unroll
      for (int i = 0; i < 4; ++i) acc[k][i] = __float2half2_rn(0.0f);

    int cmax = c_[kb] > c_[kb + 1] ? c_[kb] : c_[kb + 1];
    cmax = cmax > c_[kb + 2] ? cmax : c_[kb + 2];
    cmax = cmax > c_[kb + 3] ? cmax : c_[kb + 3];
    cmax = cmax > SLOTS ? SLOTS : cmax;
    const int nq = (cmax + 3) >> 2;   // dummy slots -> zero row: no guards

    #pragma unroll 2
    for (int j = 0; j < nq; ++j) {
      const int sl = 4 * j + q;
      #pragma unroll
      for (int k = 0; k < 4; ++k) {
        const int o = __shfl((int)pk_[kb + k], sl);
        const uint4 v = *reinterpret_cast<const uint4*>(
            fbase + (size_t)(unsigned)o + (li << 4));
        acc[k][0] = __hadd2(acc[k][0], *reinterpret_cast<const __half2*>(&v.x));
        acc[k][1] = __hadd2(acc[k][1], *reinterpret_cast<const __half2*>(&v.y));
        acc[k][2] = __hadd2(acc[k][2], *reinterpret_cast<const __half2*>(&v.z));
        acc[k][3] = __hadd2(acc[k][3], *reinterpret_cast<const __half2*>(&v.w));
      }
    }

    #pragma unroll
    for (int k = 0; k < 4; ++k) {
      #pragma unroll
      for (int i = 0; i < 4; ++i) {
        int t = __shfl_xor(*reinterpret_cast<int*>(&acc[k][i]), 32);
        acc[k][i] = __hadd2(acc[k][i], *reinterpret_cast<__half2*>(&t));
        t = __shfl_xor(*reinterpret_cast<int*>(&acc[k][i]), 16);
        acc[k][i] = __hadd2(acc[k][i], *reinterpret_cast<__half2*>(&t));
      }
      if (q == 0) {
        const int cc = c_[kb + k];
        const __half2 dn = __float2half2_rn(rsqrtf((float)(cc > 0 ? cc : 1)));
        uint4 s;
        __half2 h;
        h = __hmul2(acc[k][0], dn); s.x = *reinterpret_cast<unsigned*>(&h);
        h = __hmul2(acc[k][1], dn); s.y = *reinterpret_cast<unsigned*>(&h);
        h = __hmul2(acc[k][2], dn); s.z = *reinterpret_cast<unsigned*>(&h);
        h = __hmul2(acc[k][3], dn); s.w = *reinterpret_cast<unsigned*>(&h);
        *reinterpret_cast<uint4*>(
            aggH + (size_t)(wid + 4 * (kb + k)) * 136 + li * 8) = s;
      }
    }
  }
  __syncthreads();

  // ---- phase 2: MFMA GEMM. wave wid owns cols [32*wid, 32*wid+32) ----
  f32x4 acc00 = {0.f, 0.f, 0.f, 0.f};
  f32x4 acc01 = {0.f, 0.f, 0.f, 0.f};
  f32x4 acc10 = {0.f, 0.f, 0.f, 0.f};
  f32x4 acc11 = {0.f, 0.f, 0.f, 0.f};
  const int colbase = wid * 32 + li;

  #pragma unroll
  for (int kc = 0; kc < 4; ++kc) {
    const int k0 = kc * 32 + q * 8;
    const f16x8 a0 = *reinterpret_cast<const f16x8*>(aggH + (size_t)li * 136 + k0);
    const f16x8 a1 =
        *reinterpret_cast<const f16x8*>(aggH + (size_t)(16 + li) * 136 + k0);
    const float* w0 = W + (size_t)k0 * DIM + colbase;
    f16x8 b0, b1;
    #pragma unroll
    for (int e = 0; e < 8; ++e) {
      b0[e] = (_Float16)w0[e * DIM];
      b1[e] = (_Float16)w0[e * DIM + 16];
    }
    acc00 = __builtin_amdgcn_mfma_f32_16x16x32_f16(a0, b0, acc00, 0, 0, 0);
    acc01 = __builtin_amdgcn_mfma_f32_16x16x32_f16(a0, b1, acc01, 0, 0, 0);
    acc10 = __builtin_amdgcn_mfma_f32_16x16x32_f16(a1, b0, acc10, 0, 0, 0);
    acc11 = __builtin_amdgcn_mfma_f32_16x16x32_f16(a1, b1, acc11, 0, 0, 0);
  }
  __syncthreads();

  // D fragments -> buf (f32). D: col = lane&15, row = (lane>>4)*4 + reg.
  #pragma unroll
  for (int r = 0; r < 4; ++r) {
    const int row0 = q * 4 + r;
    buf[row0][colbase] = acc00[r];
    buf[row0][colbase + 16] = acc01[r];
    buf[row0 + 16][colbase] = acc10[r];
    buf[row0 + 16][colbase + 16] = acc11[r];
  }
  __syncthreads();

  // ---- epilogue: bias + activation + store (+ f16 prescaled copy) ----
  const int tc = tid & 31;
  const int tr = tid >> 5;
  const int c0 = tc << 2;
  const float4 bv = *reinterpret_cast<const float4*>(bias + c0);
  #pragma unroll
  for (int i = 0; i < 4; ++i) {
    const int row = tr * 4 + i;
    float4 v = *reinterpret_cast<const float4*>(&buf[row][c0]);
    v.x += bv.x; v.y += bv.y; v.z += bv.z; v.w += bv.w;
    if (ACT == 0) {
      v.x = v.x > 0.f ? v.x : expm1f(v.x);
      v.y = v.y > 0.f ? v.y : expm1f(v.y);
      v.z = v.z > 0.f ? v.z : expm1f(v.z);
      v.w = v.w > 0.f ? v.w : expm1f(v.w);
    } else {
      float m = fmaxf(fmaxf(v.x, v.y), fmaxf(v.z, v.w));
      #pragma unroll
      for (int off = 16; off >= 1; off >>= 1) m = fmaxf(m, __shfl_xor(m, off));
      v.x = expf(v.x - m);
      v.y = expf(v.y - m);
      v.z = expf(v.z - m);
      v.w = expf(v.w - m);
      float s = v.x + v.y + v.z + v.w;
      #pragma unroll
      for (int off = 16; off >= 1; off >>= 1) s += __shfl_xor(s, off);
      const float inv = 1.0f / s;
      v.x *= inv; v.y *= inv; v.z *= inv; v.w *= inv;
    }
    const size_t grow = (size_t)(brow + row);
    *reinterpret_cast<float4*>(out + grow * DIM + c0) = v;
    if (ACT == 0 && fb_out != nullptr) {
      const int dg = deg_src[grow];
      const float sn = rsqrtf((float)(dg > 0 ? dg : 1));
      ushort4 o;
      o.x = __half_as_ushort(__float2half_rn(v.x * sn));
      o.y = __half_as_ushort(__float2half_rn(v.y * sn));
      o.z = __half_as_ushort(__float2half_rn(v.z * sn));
      o.w = __half_as_ushort(__float2half_rn(v.w * sn));
      *reinterpret_cast<ushort4*>(fb_out + grow * DIM + c0) = o;
    }
  }
}

// ===========================================================================
// FALLBACK build: full dummy fill + per-edge atomic padded-CSR
// ===========================================================================
__global__ void k_dummyfill(unsigned* __restrict__ csr,
                            unsigned short* __restrict__ fbA,
                            unsigned short* __restrict__ fbB) {
  const unsigned dummy = (unsigned)N_NODES << 8;
  uint4 dv;
  dv.x = dummy; dv.y = dummy; dv.z = dummy; dv.w = dummy;
  const int i = blockIdx.x * blockDim.x + threadIdx.x;
  if (i < N_NODES * SLOTS / 4) reinterpret_cast<uint4*>(csr)[i] = dv;
  if (i < 64) reinterpret_cast<unsigned*>(fbA + (size_t)N_NODES * DIM)[i] = 0u;
  else if (i < 128)
    reinterpret_cast<unsigned*>(fbB + (size_t)N_NODES * DIM)[i - 64] = 0u;
}

__global__ void k_build(const int* __restrict__ esrc, const int* __restrict__ edst,
                        int* __restrict__ deg_src, int* __restrict__ cnt,
                        unsigned* __restrict__ csr) {
  const int i = blockIdx.x * blockDim.x + threadIdx.x;
  if (i < N_EDGES) {
    const int s = esrc[i];
    const int d = edst[i];
    atomicAdd(&deg_src[s], 1);
    const int pos = atomicAdd(&cnt[d], 1);
    csr[(size_t)d * SLOTS + pos] = (unsigned)s << 8;
  }
}

// ---------------------------------------------------------------------------
static inline size_t align1k(size_t x) { return (x + 1023) & ~(size_t)1023; }

extern "C" void kernel_launch(void* const* d_in, const int* in_sizes, int n_in,
                              void* d_out, int out_size, void* d_ws,
                              size_t ws_size, hipStream_t stream) {
  const float* x  = (const float*)d_in[0];
  const float* W1 = (const float*)d_in[1];
  const float* b1 = (const float*)d_in[2];
  const float* W2 = (const float*)d_in[3];
  const float* b2 = (const float*)d_in[4];
  const float* W3 = (const float*)d_in[5];
  const float* b3 = (const float*)d_in[6];
  const int* esrc = (const int*)d_in[7];
  const int* edst = (const int*)d_in[8];

  float* y1 = (float*)d_out;
  float* y2 = y1 + (size_t)N_NODES * DIM;
  float* y3 = y2 + (size_t)N_NODES * DIM;

  // f16 tables have one extra zero "dummy" row
  const size_t fb_bytes = (size_t)(N_NODES + 1) * DIM * 2;  // ~26.2 MB

  // ---- V2 layout ----
  {
    char* ws = (char*)d_ws;
    int* dstCur = (int*)ws;                 ws += align1k(NB * 4);
    int* srcCur = (int*)ws;                 ws += align1k(NB * 4);
    int* cnt = (int*)ws;                    ws += align1k((size_t)N_NODES * 4);
    int* deg_src = (int*)ws;                ws += align1k((size_t)N_NODES * 4);
    unsigned* csr = (unsigned*)ws;          ws += align1k((size_t)N_NODES * SLOTS * 4);
    unsigned* dstStage = (unsigned*)ws;     ws += align1k((size_t)NB * BKT_CAP * 4);
    unsigned short* srcStage = (unsigned short*)ws;
                                            ws += align1k((size_t)NB * BKT_CAP * 2);
    unsigned short* fbA = (unsigned short*)ws;  ws += align1k(fb_bytes);
    unsigned short* fbB = (unsigned short*)ws;  ws += align1k(fb_bytes);
    const size_t need_v2 = (size_t)(ws - (char*)d_ws);

    if (ws_size >= need_v2) {
      k_initcur<<<1, 256, 0, stream>>>(dstCur, srcCur, fbA, fbB);
      k_scatter<<<SC_BLOCKS, 256, 0, stream>>>(esrc, edst, dstCur, srcCur,
                                               dstStage, srcStage);
      k_csr<<<NB, 256, 0, stream>>>(dstStage, dstCur, cnt, csr);
      k_sdeg<<<NB, 256, 0, stream>>>(srcStage, srcCur, deg_src);
      k_cvt_scale<<<N_NODES * DIM / 4 / 256, 256, 0, stream>>>(x, deg_src, fbA);

      k_layer_m<0><<<N_NODES / 32, 256, 0, stream>>>(
          fbA, W1, b1, cnt, csr, deg_src, y1, fbB);
      k_layer_m<0><<<N_NODES / 32, 256, 0, stream>>>(
          fbB, W2, b2, cnt, csr, deg_src, y2, fbA);
      k_layer_m<1><<<N_NODES / 32, 256, 0, stream>>>(
          fbA, W3, b3, cnt, csr, deg_src, y3, nullptr);
      return;
    }
  }

  // ---- Fallback: atomic padded-CSR build + same f16 layers ----
  {
    char* ws = (char*)d_ws;
    int* cnt     = (int*)ws;  ws += (size_t)N_NODES * 4;
    int* deg_src = (int*)ws;  ws += (size_t)N_NODES * 4;
    unsigned* csr = (unsigned*)ws;  ws += (size_t)N_NODES * SLOTS * 4;
    unsigned short* fbA = (unsigned short*)ws;  ws += align1k(fb_bytes);
    unsigned short* fbB = (unsigned short*)ws;  ws += align1k(fb_bytes);

    (void)hipMemsetAsync(cnt, 0, (size_t)N_NODES * 2 * sizeof(int), stream);
    k_dummyfill<<<(N_NODES * SLOTS / 4 + 255) / 256, 256, 0, stream>>>(csr, fbA,
                                                                       fbB);
    k_build<<<(N_EDGES + 255) / 256, 256, 0, stream>>>(esrc, edst, deg_src,
                                                       cnt, csr);
    k_cvt_scale<<<N_NODES * DIM / 4 / 256, 256, 0, stream>>>(x, deg_src, fbA);

    k_layer_m<0><<<N_NODES / 32, 256, 0, stream>>>(
        fbA, W1, b1, cnt, csr, deg_src, y1, fbB);
    k_layer_m<0><<<N_NODES / 32, 256, 0, stream>>>(
        fbB, W2, b2, cnt, csr, deg_src, y2, fbA);
    k_layer_m<1><<<N_NODES / 32, 256, 0, stream>>>(
        fbA, W3, b3, cnt, csr, deg_src, y3, nullptr);
  }
}